// Round 12
// baseline (2101.457 us; speedup 1.0000x reference)
//
#include <hip/hip_runtime.h>
#include <hip/hip_bf16.h>
#include <math.h>

#define NN 50000
#define EE 500000
#define GG 1024
#define NDIM 32
#define EDIM 16
#define HH 128
#define LL 4
#define NT2 ((EE + 127) / 128)    // 3907 edge tiles (last V=32)
#define NB2 ((NN + 127) / 128)    // 391 node tiles
#define SCAN_NB ((NN + 255) / 256)

typedef unsigned short ushortT;
typedef __attribute__((ext_vector_type(8))) short bf16x8;
typedef __attribute__((ext_vector_type(4))) float f32x4;

#define MFMA16(a, b, c) __builtin_amdgcn_mfma_f32_16x16x32_bf16(a, b, c, 0, 0, 0)

__device__ inline float bf2f(ushortT u) {
    union { unsigned int i; float f; } v; v.i = ((unsigned int)u) << 16; return v.f;
}
__device__ inline ushortT f2bf(float f) {
    union { float f; unsigned int i; } v; v.f = f;
    unsigned int r = v.i + 0x7FFFu + ((v.i >> 16) & 1u);  // RNE
    return (ushortT)(r >> 16);
}
__device__ inline short f2bfs(float f) { return (short)f2bf(f); }

__device__ inline bf16x8 lds_a(const char* base, int strideB, int row, int colByte,
                               int mask) {
    int b = row * strideB + colByte;
    b ^= ((row & mask) << 4);
    return *reinterpret_cast<const bf16x8*>(base + b);
}

// ---------------- sort-by-dst ----------------
__global__ __launch_bounds__(256) void hist_kernel(
        const int* __restrict__ dst, int* __restrict__ counts) {
    int i = blockIdx.x * 256 + threadIdx.x;
    if (i < EE) atomicAdd(&counts[dst[i]], 1);
}

__global__ __launch_bounds__(256) void scan_part1(
        const int* __restrict__ counts, int* __restrict__ bsum) {
    __shared__ int buf[256];
    int t = threadIdx.x;
    int i = blockIdx.x * 256 + t;
    buf[t] = (i < NN) ? counts[i] : 0;
    __syncthreads();
    for (int s = 128; s > 0; s >>= 1) {
        if (t < s) buf[t] += buf[t + s];
        __syncthreads();
    }
    if (t == 0) bsum[blockIdx.x] = buf[0];
}

__global__ __launch_bounds__(256) void scan_part2(
        const int* __restrict__ bsum, int* __restrict__ bbase) {
    __shared__ int buf[256];
    int t = threadIdx.x;
    int v = (t < SCAN_NB) ? bsum[t] : 0;
    buf[t] = v;
    __syncthreads();
    for (int off = 1; off < 256; off <<= 1) {
        int s = (t >= off) ? buf[t - off] : 0;
        __syncthreads();
        buf[t] += s;
        __syncthreads();
    }
    if (t < SCAN_NB) bbase[t] = buf[t] - v;
}

__global__ __launch_bounds__(256) void scan_part3(
        const int* __restrict__ counts, const int* __restrict__ bbase,
        int* __restrict__ base) {
    __shared__ int buf[256];
    int t = threadIdx.x;
    int i = blockIdx.x * 256 + t;
    int v = (i < NN) ? counts[i] : 0;
    buf[t] = v;
    __syncthreads();
    for (int off = 1; off < 256; off <<= 1) {
        int s = (t >= off) ? buf[t - off] : 0;
        __syncthreads();
        buf[t] += s;
        __syncthreads();
    }
    if (i < NN) base[i] = bbase[blockIdx.x] + buf[t] - v;
}

__global__ __launch_bounds__(256) void build_perm_kernel(
        const int* __restrict__ src, const int* __restrict__ dst,
        const int* __restrict__ base, int* __restrict__ cnt,
        int* __restrict__ perm, int* __restrict__ srcS, int* __restrict__ dstS) {
    int i = blockIdx.x * 256 + threadIdx.x;
    if (i >= EE) return;
    int d = dst[i];
    int pos = base[d] + atomicAdd(&cnt[d], 1);
    perm[pos] = i;
    srcS[pos] = src[i];
    dstS[pos] = d;
}

// ---------------- group (batch) sort for pooling ----------------
__global__ __launch_bounds__(256) void ghist_kernel(
        const int* __restrict__ batch, int* __restrict__ gcounts) {
    int i = blockIdx.x * 256 + threadIdx.x;
    if (i < NN) atomicAdd(&gcounts[batch[i]], 1);
}

__global__ __launch_bounds__(1024) void gscan_kernel(
        const int* __restrict__ gcounts, int* __restrict__ gbase) {
    __shared__ int buf[1024];
    int t = threadIdx.x;
    int v = gcounts[t];
    buf[t] = v;
    __syncthreads();
    for (int off = 1; off < 1024; off <<= 1) {
        int s = (t >= off) ? buf[t - off] : 0;
        __syncthreads();
        buf[t] += s;
        __syncthreads();
    }
    gbase[t] = buf[t] - v;
}

__global__ __launch_bounds__(256) void gbuild_kernel(
        const int* __restrict__ batch, const int* __restrict__ gbase,
        int* __restrict__ gcnt, int* __restrict__ gperm) {
    int i = blockIdx.x * 256 + threadIdx.x;
    if (i >= NN) return;
    int b = batch[i];
    int pos = gbase[b] + atomicAdd(&gcnt[b], 1);
    gperm[pos] = i;
}

// ---------------- weight prep ----------------
__global__ __launch_bounds__(256) void transpose_kernel(
        const float* __restrict__ in, ushortT* __restrict__ out, int K, int N) {
    int per = K * N;
    int total = LL * per;
    int idx = blockIdx.x * 256 + threadIdx.x;
    if (idx >= total) return;
    int l = idx / per, rem = idx - l * per;
    int n = rem / K, k = rem - n * K;
    out[idx] = f2bf(in[(size_t)l * per + (size_t)k * N + n]);
}

// fp32 [KIN][128] -> bf16 [128][32] zero-padded beyond KIN
__global__ __launch_bounds__(256) void transpose_pad32_kernel(
        const float* __restrict__ in, ushortT* __restrict__ out, int KIN) {
    int idx = blockIdx.x * 256 + threadIdx.x;
    if (idx >= HH * 32) return;
    int n = idx >> 5, k = idx & 31;
    out[idx] = (k < KIN) ? f2bf(in[k * HH + n]) : (ushortT)0;
}

__global__ __launch_bounds__(256) void bnfold_kernel(
        const float* __restrict__ w2, const float* __restrict__ b2,
        const float* __restrict__ bng, const float* __restrict__ bnb,
        ushortT* __restrict__ w2g, float* __restrict__ nb2g, float inv_std) {
    int idx = blockIdx.x * 256 + threadIdx.x;
    if (idx < LL * HH * HH) {
        int l = idx / (HH * HH), rem = idx - l * (HH * HH);
        int n = rem / HH, k = rem - n * HH;
        w2g[idx] = f2bf(w2[(size_t)l * HH * HH + (size_t)k * HH + n] *
                        bng[l * HH + n] * inv_std);
    }
    if (idx < LL * HH) {
        nb2g[idx] = b2[idx] * bng[idx] * inv_std + bnb[idx];
    }
}

// ---------------- GEMM helpers: 8x1 wave grid, wave w owns rows [w*16,w*16+16),
// all 128 output cols. acc[8] f32x4 = 16x128 C per wave. No cross-wave LDS deps.
template<int K, int KS, bool HASB>
__device__ inline void gemm_w(const char* aBase, int aStrideB, int aMask,
        const ushortT* __restrict__ wT, const float* __restrict__ bias,
        int w, int l15, int lg, f32x4 acc[8]) {
#pragma unroll
    for (int n = 0; n < 8; ++n) {
        float bb = HASB ? bias[n * 16 + l15] : 0.f;
        f32x4 iv = {bb, bb, bb, bb};
        acc[n] = iv;
    }
#pragma unroll
    for (int ks = 0; ks < K / 32; ++ks) {
        int kk = ks * 32 + lg * 8;
        bf16x8 a0 = lds_a(aBase, aStrideB, w * 16 + l15, kk * 2, aMask);
#pragma unroll
        for (int n = 0; n < 8; ++n) {
            bf16x8 b = *reinterpret_cast<const bf16x8*>(
                wT + (size_t)(n * 16 + l15) * KS + kk);
            acc[n] = MFMA16(a0, b, acc[n]);
        }
    }
}

__device__ inline void wfrag_w(char* base, int w, int l15, int lg,
                               f32x4 acc[8], bool relu) {
#pragma unroll
    for (int n = 0; n < 8; ++n) {
        int col = n * 16 + l15;
#pragma unroll
        for (int r = 0; r < 4; ++r) {
            int row = w * 16 + lg * 4 + r;
            int b = row * 256 + col * 2;
            b ^= ((row & 7) << 4);
            float v = acc[n][r];
            if (relu) v = fmaxf(v, 0.f);
            *reinterpret_cast<ushortT*>(base + b) = f2bf(v);
        }
    }
}

// G3: C-init from uT (bf16 swz7), A = eT rows w*16.., B = nw1t_l+128 (KS=256)
__device__ inline void gemm_uinit_w(const char* aBase, const char* uBase,
        const ushortT* __restrict__ wT, int w, int l15, int lg, f32x4 acc[8]) {
#pragma unroll
    for (int n = 0; n < 8; ++n) {
        int col = n * 16 + l15;
#pragma unroll
        for (int r = 0; r < 4; ++r) {
            int row = w * 16 + lg * 4 + r;
            int b = row * 256 + col * 2; b ^= ((row & 7) << 4);
            acc[n][r] = bf2f(*reinterpret_cast<const ushortT*>(uBase + b));
        }
    }
#pragma unroll
    for (int ks = 0; ks < 4; ++ks) {
        int kk = ks * 32 + lg * 8;
        bf16x8 a0 = lds_a(aBase, 256, w * 16 + l15, kk * 2, 7);
#pragma unroll
        for (int n = 0; n < 8; ++n) {
            bf16x8 b = *reinterpret_cast<const bf16x8*>(
                wT + (size_t)(n * 16 + l15) * 256 + kk);
            acc[n] = MFMA16(a0, b, acc[n]);
        }
    }
}

// ---------------- A: edge kernel (8x1 wave-row-ownership, ONE barrier) --------
template<int EMBED, int LASTL>
__global__ __launch_bounds__(512) void edgeA_kernel(
        const ushortT* __restrict__ u, ushortT* __restrict__ e,
        const int* __restrict__ srcS, const int* __restrict__ dstS,
        const int* __restrict__ basep, const int* __restrict__ perm,
        const float* __restrict__ ea,
        const ushortT* __restrict__ eewT, const float* __restrict__ eeb,
        const ushortT* __restrict__ ew1t, const float* __restrict__ eb1,
        const ushortT* __restrict__ ew2t, const float* __restrict__ eb2,
        const ushortT* __restrict__ nw1bt,   // nw1t_l + 128 (KS=256)
        ushortT* __restrict__ partials) {
    __shared__ __align__(16) char eT[128 * 256];
    __shared__ __align__(16) char uT[128 * 256];
    __shared__ __align__(16) char eaT[EMBED ? 128 * 64 : 16];
    __shared__ int dstx[128], bstartL[128];

    const int e0 = blockIdx.x * 128;
    int V = EE - e0; if (V > 128) V = 128;
    const int tid = threadIdx.x;
    const int w = tid >> 6, lane = tid & 63, l15 = lane & 15, lg = lane >> 4;
    const bf16x8 z8 = {0, 0, 0, 0, 0, 0, 0, 0};

    // per-wave: dst/base ints for own rows (consumed after the single barrier)
    if (lane < 16) {
        int rr = w * 16 + lane;
        int ii = e0 + rr;
        int d = (ii < EE) ? dstS[ii] : -1;
        dstx[rr] = d;
        bstartL[rr] = (d >= 0) ? basep[d] : 0;
    }
    // stage u[src] for own rows: 16 rows x 16 chunks, 4 chunks/lane
#pragma unroll
    for (int s = 0; s < 4; ++s) {
        int c = lane + s * 64;
        int rr = w * 16 + (c >> 4);
        int c8 = (c & 15) * 8;
        int ii = e0 + rr;
        bf16x8 v = z8;
        if (ii < EE) {
            int sI = srcS[ii];
            v = *reinterpret_cast<const bf16x8*>(u + (size_t)sI * HH + c8);
        }
        int b = rr * 256 + c8 * 2; b ^= ((rr & 7) << 4);
        *reinterpret_cast<bf16x8*>(uT + b) = v;
    }
    if (EMBED) {
        // stage ea[perm] own rows into eaT [128][32] bf16 swz3
        {
            int rr = w * 16 + (lane >> 2);
            int q4 = (lane & 3) * 4;
            int ii = e0 + rr;
            unsigned long long pack = 0ull;
            if (ii < EE) {
                int pp = perm[ii];
                float4 v = *reinterpret_cast<const float4*>(
                    ea + (size_t)pp * EDIM + q4);
                pack = (unsigned long long)f2bf(v.x) |
                       ((unsigned long long)f2bf(v.y) << 16) |
                       ((unsigned long long)f2bf(v.z) << 32) |
                       ((unsigned long long)f2bf(v.w) << 48);
            }
            int b = rr * 64 + q4 * 2; b ^= ((rr & 3) << 4);
            *reinterpret_cast<unsigned long long*>(eaT + b) = pack;
        }
        if (lane < 32) {
            int rr = w * 16 + (lane >> 1);
            int b = rr * 64 + 32 + (lane & 1) * 16; b ^= ((rr & 3) << 4);
            *reinterpret_cast<bf16x8*>(eaT + b) = z8;
        }
    } else {
        // stage e own rows
#pragma unroll
        for (int s = 0; s < 4; ++s) {
            int c = lane + s * 64;
            int rr = w * 16 + (c >> 4);
            int c8 = (c & 15) * 8;
            int ii = e0 + rr;
            bf16x8 v = z8;
            if (ii < EE)
                v = *reinterpret_cast<const bf16x8*>(e + (size_t)ii * HH + c8);
            int b = rr * 256 + c8 * 2; b ^= ((rr & 7) << 4);
            *reinterpret_cast<bf16x8*>(eT + b) = v;
        }
    }
    // NO barrier: all phases below stay within this wave's 16-row stripe.

    f32x4 acc[8];
    if (EMBED) {
        gemm_w<32, 32, true>(eaT, 64, 3, eewT, eeb, w, l15, lg, acc);
        wfrag_w(eT, w, l15, lg, acc, false);
    }
    // em1: hid = relu(e @ ew1 + eb1), in-place own rows
    gemm_w<HH, HH, true>(eT, 256, 7, ew1t, eb1, w, l15, lg, acc);
    wfrag_w(eT, w, l15, lg, acc, true);
    // em2: e' = hid @ ew2 + eb2, in-place own rows
    gemm_w<HH, HH, true>(eT, 256, 7, ew2t, eb2, w, l15, lg, acc);
    wfrag_w(eT, w, l15, lg, acc, false);
    // e' copy-out own rows
    if (!LASTL) {
#pragma unroll
        for (int s = 0; s < 4; ++s) {
            int c = lane + s * 64;
            int rr = w * 16 + (c >> 4);
            int c8 = (c & 15) * 8;
            int ii = e0 + rr;
            if (ii < EE) {
                int b = rr * 256 + c8 * 2; b ^= ((rr & 7) << 4);
                *reinterpret_cast<bf16x8*>(e + (size_t)ii * HH + c8) =
                    *reinterpret_cast<const bf16x8*>(eT + b);
            }
        }
    }
    // G3: hidden = relu(u + e' @ W1b), C-init from uT, in-place own rows
    gemm_uinit_w(eT, uT, nw1bt, w, l15, lg, acc);
    wfrag_w(eT, w, l15, lg, acc, true);
    __syncthreads();   // the ONLY barrier: hidden + dstx visible block-wide

    // segmented sum of hidden (eT) by dst: 128 cols x 4 segs of 32 rows
    {
        int col = tid & 127, seg = tid >> 7;
        int r = seg * 32, rend = r + 32;
        float sum = 0.f;
        int dprev = -1, runStart = r;
        for (; r < rend; ++r) {
            int d = dstx[r];
            if (d != dprev) {
                if (dprev >= 0) {
                    int slot = ((e0 + runStart) >> 5) - (bstartL[runStart] >> 5);
                    if (slot < 3)
                        partials[((size_t)slot * NN + dprev) * HH + col] = f2bf(sum);
                }
                sum = 0.f; dprev = d; runStart = r;
            }
            if (d >= 0) {
                int b = r * 256 + col * 2; b ^= ((r & 7) << 4);
                sum += bf2f(*reinterpret_cast<const ushortT*>(eT + b));
            }
        }
        if (dprev >= 0) {
            int slot = ((e0 + runStart) >> 5) - (bstartL[runStart] >> 5);
            if (slot < 3)
                partials[((size_t)slot * NN + dprev) * HH + col] = f2bf(sum);
        }
    }
}

// ---------------- B: node kernel (8x1, ZERO barriers) ----------------
template<int HASU>
__global__ __launch_bounds__(512) void nodeB_kernel(
        const ushortT* __restrict__ partials, const int* __restrict__ basep,
        const ushortT* __restrict__ w2g, const float* __restrict__ nb2g,
        float* __restrict__ h,
        const ushortT* __restrict__ w1tn, const float* __restrict__ b1n,
        ushortT* __restrict__ uOut) {
    __shared__ __align__(16) char sT[128 * 256];
    const int n0 = blockIdx.x * 128;
    int V = NN - n0; if (V > 128) V = 128;
    const int tid = threadIdx.x;
    const int w = tid >> 6, lane = tid & 63, l15 = lane & 15, lg = lane >> 4;

    // per-wave: Sigma_hid for own 16 rows -> sT (bf16 swz7)
#pragma unroll
    for (int s = 0; s < 4; ++s) {
        int c = lane + s * 64;
        int node = w * 16 + (c >> 4);
        int c8 = (c & 15) * 8;
        float sm[8] = {0.f, 0.f, 0.f, 0.f, 0.f, 0.f, 0.f, 0.f};
        if (node < V) {
            int n = n0 + node;
            int bs = basep[n];
            int be = (n + 1 < NN) ? basep[n + 1] : EE;
            int de = be - bs;
            if (de > 0) {
                int ns = ((bs + de - 1) >> 5) - (bs >> 5) + 1;
                if (ns > 3) ns = 3;
                for (int sl = 0; sl < ns; ++sl) {
                    bf16x8 pv = *reinterpret_cast<const bf16x8*>(
                        partials + ((size_t)sl * NN + n) * HH + c8);
#pragma unroll
                    for (int j = 0; j < 8; ++j) sm[j] += bf2f((ushortT)pv[j]);
                }
            }
        }
        bf16x8 o;
#pragma unroll
        for (int j = 0; j < 8; ++j) o[j] = f2bfs(sm[j]);
        int b = node * 256 + c8 * 2; b ^= ((node & 7) << 4);
        *reinterpret_cast<bf16x8*>(sT + b) = o;
    }

    f32x4 acc[8];
    gemm_w<HH, HH, false>(sT, 256, 7, w2g, nullptr, w, l15, lg, acc);
    // h_new = h + Sigma_msg + deg*nb2g (in-place global), own rows
#pragma unroll
    for (int n8 = 0; n8 < 8; ++n8) {
        int col = n8 * 16 + l15;
        float bg = nb2g[col];
#pragma unroll
        for (int r = 0; r < 4; ++r) {
            int row = w * 16 + lg * 4 + r;
            if (row < V) {
                int n = n0 + row;
                int bs = basep[n];
                int be = (n + 1 < NN) ? basep[n + 1] : EE;
                size_t off = (size_t)n * HH + col;
                float hn = h[off] + acc[n8][r] + (float)(be - bs) * bg;
                h[off] = hn;
                acc[n8][r] = hn;
            } else {
                acc[n8][r] = 0.f;
            }
        }
    }
    if (HASU) {
        wfrag_w(sT, w, l15, lg, acc, false);   // bf16(h_new) own rows
        gemm_w<HH, 2 * HH, true>(sT, 256, 7, w1tn, b1n, w, l15, lg, acc);
        wfrag_w(sT, w, l15, lg, acc, false);
#pragma unroll
        for (int s = 0; s < 4; ++s) {
            int c = lane + s * 64;
            int rr = w * 16 + (c >> 4);
            int c8 = (c & 15) * 8;
            if (rr < V) {
                int b = rr * 256 + c8 * 2; b ^= ((rr & 7) << 4);
                *reinterpret_cast<bf16x8*>(uOut + (size_t)(n0 + rr) * HH + c8) =
                    *reinterpret_cast<const bf16x8*>(sT + b);
            }
        }
    }
}

// ---------------- node_pre2 (8x1, zero barriers): h = x@ne_w+ne_b ; u0 --------
__global__ __launch_bounds__(512) void node_pre2_kernel(
        const float* __restrict__ x, const ushortT* __restrict__ newT,
        const float* __restrict__ neb,
        const ushortT* __restrict__ w1t, const float* __restrict__ b1,
        float* __restrict__ h, ushortT* __restrict__ uo) {
    __shared__ __align__(16) char sT[128 * 256];
    __shared__ __align__(16) char xT[128 * 64];
    const int n0 = blockIdx.x * 128;
    int V = NN - n0; if (V > 128) V = 128;
    const int tid = threadIdx.x;
    const int w = tid >> 6, lane = tid & 63, l15 = lane & 15, lg = lane >> 4;

    // stage x own rows: 16 rows x 8 float4 chunks = 128, 2/lane
#pragma unroll
    for (int s = 0; s < 2; ++s) {
        int c = lane + s * 64;            // 0..127
        int rr = w * 16 + (c >> 3);
        int q4 = (c & 7) * 4;
        unsigned long long pack = 0ull;
        if (rr < V) {
            float4 v = *reinterpret_cast<const float4*>(
                x + (size_t)(n0 + rr) * NDIM + q4);
            pack = (unsigned long long)f2bf(v.x) |
                   ((unsigned long long)f2bf(v.y) << 16) |
                   ((unsigned long long)f2bf(v.z) << 32) |
                   ((unsigned long long)f2bf(v.w) << 48);
        }
        int b = rr * 64 + q4 * 2; b ^= ((rr & 3) << 4);
        *reinterpret_cast<unsigned long long*>(xT + b) = pack;
    }

    f32x4 acc[8];
    gemm_w<32, 32, true>(xT, 64, 3, newT, neb, w, l15, lg, acc);
    // write h (fp32) own rows
#pragma unroll
    for (int n8 = 0; n8 < 8; ++n8) {
        int col = n8 * 16 + l15;
#pragma unroll
        for (int r = 0; r < 4; ++r) {
            int row = w * 16 + lg * 4 + r;
            if (row < V) h[(size_t)(n0 + row) * HH + col] = acc[n8][r];
        }
    }
    wfrag_w(sT, w, l15, lg, acc, false);
    gemm_w<HH, 2 * HH, true>(sT, 256, 7, w1t, b1, w, l15, lg, acc);
    wfrag_w(sT, w, l15, lg, acc, false);
#pragma unroll
    for (int s = 0; s < 4; ++s) {
        int c = lane + s * 64;
        int rr = w * 16 + (c >> 4);
        int c8 = (c & 15) * 8;
        if (rr < V) {
            int b = rr * 256 + c8 * 2; b ^= ((rr & 7) << 4);
            *reinterpret_cast<bf16x8*>(uo + (size_t)(n0 + rr) * HH + c8) =
                *reinterpret_cast<const bf16x8*>(sT + b);
        }
    }
}

// ---------------- pool (group-sorted, atomic-free) + readout ----------------
__global__ __launch_bounds__(256) void pool2_kernel(
        const float* __restrict__ h, const int* __restrict__ gperm,
        const int* __restrict__ gbase, const int* __restrict__ gcounts,
        float* __restrict__ pooled) {
    int w = threadIdx.x >> 6, lane = threadIdx.x & 63;
    int g = blockIdx.x * 4 + w;
    int bs = gbase[g], cnt = gcounts[g];
    int c = lane * 2;
    float ax = 0.f, ay = 0.f;
    for (int j = 0; j < cnt; ++j) {
        int n = gperm[bs + j];
        float2 v = *reinterpret_cast<const float2*>(h + (size_t)n * HH + c);
        ax += v.x; ay += v.y;
    }
    float2 o = {ax, ay};
    *reinterpret_cast<float2*>(pooled + (size_t)g * HH + c) = o;
}

__global__ __launch_bounds__(128) void readout_kernel(
        const float* __restrict__ pooled,
        const float* __restrict__ w1, const float* __restrict__ b1,
        const float* __restrict__ w2, const float* __restrict__ b2,
        float* __restrict__ out) {
    __shared__ float row[HH];
    __shared__ float red[HH];
    int g = blockIdx.x, j = threadIdx.x;
    row[j] = pooled[(size_t)g * HH + j];
    __syncthreads();
    float acc = b1[j];
    for (int k = 0; k < HH; ++k) acc += row[k] * w1[k * HH + j];
    red[j] = fmaxf(acc, 0.f) * w2[j];
    __syncthreads();
    for (int s = 64; s > 0; s >>= 1) {
        if (j < s) red[j] += red[j + s];
        __syncthreads();
    }
    if (j == 0) out[g] = red[0] + b2[0];
}

extern "C" void kernel_launch(void* const* d_in, const int* in_sizes, int n_in,
                              void* d_out, int out_size, void* d_ws, size_t ws_size,
                              hipStream_t stream) {
    const float* x     = (const float*)d_in[0];
    const int*   ei    = (const int*)d_in[1];
    const float* ea    = (const float*)d_in[2];
    const int*   batch = (const int*)d_in[3];
    const float* ne_w  = (const float*)d_in[4];
    const float* ne_b  = (const float*)d_in[5];
    const float* ee_w  = (const float*)d_in[6];
    const float* ee_b  = (const float*)d_in[7];
    const float* nm_w1 = (const float*)d_in[8];
    const float* nm_b1 = (const float*)d_in[9];
    const float* nm_w2 = (const float*)d_in[10];
    const float* nm_b2 = (const float*)d_in[11];
    const float* bn_g  = (const float*)d_in[12];
    const float* bn_b  = (const float*)d_in[13];
    const float* em_w1 = (const float*)d_in[14];
    const float* em_b1 = (const float*)d_in[15];
    const float* em_w2 = (const float*)d_in[16];
    const float* em_b2 = (const float*)d_in[17];
    const float* ro_w1 = (const float*)d_in[18];
    const float* ro_b1 = (const float*)d_in[19];
    const float* ro_w2 = (const float*)d_in[20];
    const float* ro_b2 = (const float*)d_in[21];

    const int* srcp = ei;
    const int* dstp = ei + EE;

    // workspace carve (16B aligned) — total ~214 MB
    char* p = (char*)d_ws;
    float* h = (float*)p;            p += (size_t)NN * HH * 4;
    float* pooled = (float*)p;       p += (size_t)GG * HH * 4;
    ushortT* ebuf = (ushortT*)p;     p += (size_t)EE * HH * 2;
    ushortT* ubuf = (ushortT*)p;     p += (size_t)NN * HH * 2;
    ushortT* partials = (ushortT*)p; p += (size_t)3 * NN * HH * 2;
    ushortT* ew1t = (ushortT*)p;     p += (size_t)LL * HH * HH * 2;
    ushortT* ew2t = (ushortT*)p;     p += (size_t)LL * HH * HH * 2;
    ushortT* nw1t = (ushortT*)p;     p += (size_t)LL * 2 * HH * HH * 2;
    ushortT* w2g  = (ushortT*)p;     p += (size_t)LL * HH * HH * 2;
    float* nb2g   = (float*)p;       p += (size_t)LL * HH * 4;
    ushortT* eewT = (ushortT*)p;     p += (size_t)HH * 32 * 2;
    ushortT* newT = (ushortT*)p;     p += (size_t)HH * 32 * 2;
    int* perm   = (int*)p;           p += (size_t)EE * 4;
    int* srcS   = (int*)p;           p += (size_t)EE * 4;
    int* dstS   = (int*)p;           p += (size_t)EE * 4;
    int* counts = (int*)p;           p += (size_t)NN * 4;
    int* basep  = (int*)p;           p += (size_t)NN * 4;
    int* cnt    = (int*)p;           p += (size_t)NN * 4;
    int* bsum   = (int*)p;           p += (size_t)SCAN_NB * 4;
    int* bbase  = (int*)p;           p += (size_t)SCAN_NB * 4;
    int* gperm  = (int*)p;           p += (size_t)NN * 4;
    int* gcounts= (int*)p;           p += (size_t)GG * 4;
    int* gbase  = (int*)p;           p += (size_t)GG * 4;
    int* gcnt   = (int*)p;           p += (size_t)GG * 4;

    // ---- sort edges by dst ----
    hipMemsetAsync(counts, 0, (size_t)NN * 4, stream);
    hipMemsetAsync(cnt, 0, (size_t)NN * 4, stream);
    hipMemsetAsync(gcounts, 0, (size_t)GG * 4, stream);
    hipMemsetAsync(gcnt, 0, (size_t)GG * 4, stream);
    hist_kernel<<<(EE + 255) / 256, 256, 0, stream>>>(dstp, counts);
    scan_part1<<<SCAN_NB, 256, 0, stream>>>(counts, bsum);
    scan_part2<<<1, 256, 0, stream>>>(bsum, bbase);
    scan_part3<<<SCAN_NB, 256, 0, stream>>>(counts, bbase, basep);
    build_perm_kernel<<<(EE + 255) / 256, 256, 0, stream>>>(
        srcp, dstp, basep, cnt, perm, srcS, dstS);

    // ---- sort nodes by batch group (for atomic-free pooling) ----
    ghist_kernel<<<(NN + 255) / 256, 256, 0, stream>>>(batch, gcounts);
    gscan_kernel<<<1, 1024, 0, stream>>>(gcounts, gbase);
    gbuild_kernel<<<(NN + 255) / 256, 256, 0, stream>>>(batch, gbase, gcnt, gperm);

    // ---- weight prep ----
    const float inv_std = 1.0f / sqrtf(1.0f + 1e-5f);
    transpose_kernel<<<(LL * HH * HH + 255) / 256, 256, 0, stream>>>(em_w1, ew1t, HH, HH);
    transpose_kernel<<<(LL * HH * HH + 255) / 256, 256, 0, stream>>>(em_w2, ew2t, HH, HH);
    transpose_kernel<<<(LL * 2 * HH * HH + 255) / 256, 256, 0, stream>>>(nm_w1, nw1t, 2 * HH, HH);
    bnfold_kernel<<<(LL * HH * HH + 255) / 256, 256, 0, stream>>>(
        nm_w2, nm_b2, bn_g, bn_b, w2g, nb2g, inv_std);
    transpose_pad32_kernel<<<(HH * 32 + 255) / 256, 256, 0, stream>>>(ee_w, eewT, EDIM);
    transpose_pad32_kernel<<<(HH * 32 + 255) / 256, 256, 0, stream>>>(ne_w, newT, NDIM);

    // ---- node embed + u0 (fused) ----
    node_pre2_kernel<<<NB2, 512, 0, stream>>>(x, newT, ne_b, nw1t, nm_b1, h, ubuf);

    // ---- layers ----
    for (int l = 0; l < LL; ++l) {
        const ushortT* nw1bt = nw1t + (size_t)l * 2 * HH * HH + 128;
        if (l == 0) {
            edgeA_kernel<1, 0><<<NT2, 512, 0, stream>>>(
                ubuf, ebuf, srcS, dstS, basep, perm, ea, eewT, ee_b,
                ew1t + (size_t)l * HH * HH, em_b1 + l * HH,
                ew2t + (size_t)l * HH * HH, em_b2 + l * HH,
                nw1bt, partials);
        } else if (l < LL - 1) {
            edgeA_kernel<0, 0><<<NT2, 512, 0, stream>>>(
                ubuf, ebuf, srcS, dstS, basep, perm, ea, eewT, ee_b,
                ew1t + (size_t)l * HH * HH, em_b1 + l * HH,
                ew2t + (size_t)l * HH * HH, em_b2 + l * HH,
                nw1bt, partials);
        } else {
            edgeA_kernel<0, 1><<<NT2, 512, 0, stream>>>(
                ubuf, ebuf, srcS, dstS, basep, perm, ea, eewT, ee_b,
                ew1t + (size_t)l * HH * HH, em_b1 + l * HH,
                ew2t + (size_t)l * HH * HH, em_b2 + l * HH,
                nw1bt, partials);
        }
        if (l < LL - 1) {
            nodeB_kernel<1><<<NB2, 512, 0, stream>>>(
                partials, basep, w2g + (size_t)l * HH * HH, nb2g + l * HH, h,
                nw1t + (size_t)(l + 1) * 2 * HH * HH, nm_b1 + (l + 1) * HH, ubuf);
        } else {
            nodeB_kernel<0><<<NB2, 512, 0, stream>>>(
                partials, basep, w2g + (size_t)l * HH * HH, nb2g + l * HH, h,
                nw1t, nm_b1, ubuf);
        }
    }

    // ---- pool + readout ----
    pool2_kernel<<<GG / 4, 256, 0, stream>>>(h, gperm, gbase, gcounts, pooled);
    readout_kernel<<<GG, 128, 0, stream>>>(pooled, ro_w1, ro_b1, ro_w2, ro_b2,
                                           (float*)d_out);
}

// Round 13
// 1177.765 us; speedup vs baseline: 1.7843x; 1.7843x over previous
//
#include <hip/hip_runtime.h>
#include <hip/hip_bf16.h>
#include <math.h>

#define NN 50000
#define EE 500000
#define GG 1024
#define NDIM 32
#define EDIM 16
#define HH 128
#define LL 4
#define TE 64
#define NTE ((EE + TE - 1) / TE)   // 7813 edge tiles (last V=32)
#define NB2 ((NN + 127) / 128)     // 391 node tiles
#define SCAN_NB ((NN + 255) / 256)

typedef unsigned short ushortT;
typedef __attribute__((ext_vector_type(8))) short bf16x8;
typedef __attribute__((ext_vector_type(4))) float f32x4;

#define MFMA16(a, b, c) __builtin_amdgcn_mfma_f32_16x16x32_bf16(a, b, c, 0, 0, 0)

__device__ inline float bf2f(ushortT u) {
    union { unsigned int i; float f; } v; v.i = ((unsigned int)u) << 16; return v.f;
}
__device__ inline ushortT f2bf(float f) {
    union { float f; unsigned int i; } v; v.f = f;
    unsigned int r = v.i + 0x7FFFu + ((v.i >> 16) & 1u);  // RNE
    return (ushortT)(r >> 16);
}
__device__ inline short f2bfs(float f) { return (short)f2bf(f); }

__device__ inline bf16x8 lds_a(const char* base, int strideB, int row, int colByte,
                               int mask) {
    int b = row * strideB + colByte;
    b ^= ((row & mask) << 4);
    return *reinterpret_cast<const bf16x8*>(base + b);
}

// ---------------- sort-by-dst ----------------
__global__ __launch_bounds__(256) void hist_kernel(
        const int* __restrict__ dst, int* __restrict__ counts) {
    int i = blockIdx.x * 256 + threadIdx.x;
    if (i < EE) atomicAdd(&counts[dst[i]], 1);
}

__global__ __launch_bounds__(256) void scan_part1(
        const int* __restrict__ counts, int* __restrict__ bsum) {
    __shared__ int buf[256];
    int t = threadIdx.x;
    int i = blockIdx.x * 256 + t;
    buf[t] = (i < NN) ? counts[i] : 0;
    __syncthreads();
    for (int s = 128; s > 0; s >>= 1) {
        if (t < s) buf[t] += buf[t + s];
        __syncthreads();
    }
    if (t == 0) bsum[blockIdx.x] = buf[0];
}

__global__ __launch_bounds__(256) void scan_part2(
        const int* __restrict__ bsum, int* __restrict__ bbase) {
    __shared__ int buf[256];
    int t = threadIdx.x;
    int v = (t < SCAN_NB) ? bsum[t] : 0;
    buf[t] = v;
    __syncthreads();
    for (int off = 1; off < 256; off <<= 1) {
        int s = (t >= off) ? buf[t - off] : 0;
        __syncthreads();
        buf[t] += s;
        __syncthreads();
    }
    if (t < SCAN_NB) bbase[t] = buf[t] - v;
}

__global__ __launch_bounds__(256) void scan_part3(
        const int* __restrict__ counts, const int* __restrict__ bbase,
        int* __restrict__ base) {
    __shared__ int buf[256];
    int t = threadIdx.x;
    int i = blockIdx.x * 256 + t;
    int v = (i < NN) ? counts[i] : 0;
    buf[t] = v;
    __syncthreads();
    for (int off = 1; off < 256; off <<= 1) {
        int s = (t >= off) ? buf[t - off] : 0;
        __syncthreads();
        buf[t] += s;
        __syncthreads();
    }
    if (i < NN) base[i] = bbase[blockIdx.x] + buf[t] - v;
}

__global__ __launch_bounds__(256) void build_perm_kernel(
        const int* __restrict__ src, const int* __restrict__ dst,
        const int* __restrict__ base, int* __restrict__ cnt,
        int* __restrict__ perm, int* __restrict__ srcS, int* __restrict__ dstS) {
    int i = blockIdx.x * 256 + threadIdx.x;
    if (i >= EE) return;
    int d = dst[i];
    int pos = base[d] + atomicAdd(&cnt[d], 1);
    perm[pos] = i;
    srcS[pos] = src[i];
    dstS[pos] = d;
}

// ---------------- group (batch) sort for pooling ----------------
__global__ __launch_bounds__(256) void ghist_kernel(
        const int* __restrict__ batch, int* __restrict__ gcounts) {
    int i = blockIdx.x * 256 + threadIdx.x;
    if (i < NN) atomicAdd(&gcounts[batch[i]], 1);
}

__global__ __launch_bounds__(1024) void gscan_kernel(
        const int* __restrict__ gcounts, int* __restrict__ gbase) {
    __shared__ int buf[1024];
    int t = threadIdx.x;
    int v = gcounts[t];
    buf[t] = v;
    __syncthreads();
    for (int off = 1; off < 1024; off <<= 1) {
        int s = (t >= off) ? buf[t - off] : 0;
        __syncthreads();
        buf[t] += s;
        __syncthreads();
    }
    gbase[t] = buf[t] - v;
}

__global__ __launch_bounds__(256) void gbuild_kernel(
        const int* __restrict__ batch, const int* __restrict__ gbase,
        int* __restrict__ gcnt, int* __restrict__ gperm) {
    int i = blockIdx.x * 256 + threadIdx.x;
    if (i >= NN) return;
    int b = batch[i];
    int pos = gbase[b] + atomicAdd(&gcnt[b], 1);
    gperm[pos] = i;
}

// ---------------- weight prep ----------------
__global__ __launch_bounds__(256) void transpose_kernel(
        const float* __restrict__ in, ushortT* __restrict__ out, int K, int N) {
    int per = K * N;
    int total = LL * per;
    int idx = blockIdx.x * 256 + threadIdx.x;
    if (idx >= total) return;
    int l = idx / per, rem = idx - l * per;
    int n = rem / K, k = rem - n * K;
    out[idx] = f2bf(in[(size_t)l * per + (size_t)k * N + n]);
}

// fp32 [KIN][128] -> bf16 [128][32] zero-padded beyond KIN
__global__ __launch_bounds__(256) void transpose_pad32_kernel(
        const float* __restrict__ in, ushortT* __restrict__ out, int KIN) {
    int idx = blockIdx.x * 256 + threadIdx.x;
    if (idx >= HH * 32) return;
    int n = idx >> 5, k = idx & 31;
    out[idx] = (k < KIN) ? f2bf(in[k * HH + n]) : (ushortT)0;
}

__global__ __launch_bounds__(256) void bnfold_kernel(
        const float* __restrict__ w2, const float* __restrict__ b2,
        const float* __restrict__ bng, const float* __restrict__ bnb,
        ushortT* __restrict__ w2g, float* __restrict__ nb2g, float inv_std) {
    int idx = blockIdx.x * 256 + threadIdx.x;
    if (idx < LL * HH * HH) {
        int l = idx / (HH * HH), rem = idx - l * (HH * HH);
        int n = rem / HH, k = rem - n * HH;
        w2g[idx] = f2bf(w2[(size_t)l * HH * HH + (size_t)k * HH + n] *
                        bng[l * HH + n] * inv_std);
    }
    if (idx < LL * HH) {
        nb2g[idx] = b2[idx] * bng[idx] * inv_std + bnb[idx];
    }
}

// ---------------- GEMM helpers (wave (wr,wc): rows wr*32+[0,32), cols wc*64) --
template<int K, int KS, bool HASB>
__device__ inline void gemm_b(const char* aBase, int aStrideB, int aMask,
        const ushortT* __restrict__ wT, const float* __restrict__ bias,
        int wr, int wc, int l15, int lg, f32x4 acc[2][4]) {
#pragma unroll
    for (int ntl = 0; ntl < 4; ++ntl) {
        float bb = HASB ? bias[wc * 64 + ntl * 16 + l15] : 0.f;
        f32x4 iv = {bb, bb, bb, bb};
        acc[0][ntl] = iv;
        acc[1][ntl] = iv;
    }
#pragma unroll
    for (int ks = 0; ks < K / 32; ++ks) {
        int kk = ks * 32 + lg * 8;
        bf16x8 a0 = lds_a(aBase, aStrideB, wr * 32 + l15,      kk * 2, aMask);
        bf16x8 a1 = lds_a(aBase, aStrideB, wr * 32 + 16 + l15, kk * 2, aMask);
#pragma unroll
        for (int ntl = 0; ntl < 4; ++ntl) {
            int n = wc * 64 + ntl * 16 + l15;
            bf16x8 b = *reinterpret_cast<const bf16x8*>(wT + (size_t)n * KS + kk);
            acc[0][ntl] = MFMA16(a0, b, acc[0][ntl]);
            acc[1][ntl] = MFMA16(a1, b, acc[1][ntl]);
        }
    }
}

// G3: acc init from uT (bf16 swz7), A=eT, B = nw1t_l+128 (KS=256)
__device__ inline void gemm_uinit3(const char* aBase, const char* uBase,
        const ushortT* __restrict__ wT,
        int wr, int wc, int l15, int lg, f32x4 acc[2][4]) {
#pragma unroll
    for (int mt = 0; mt < 2; ++mt)
#pragma unroll
        for (int ntl = 0; ntl < 4; ++ntl) {
            int col = wc * 64 + ntl * 16 + l15;
#pragma unroll
            for (int r = 0; r < 4; ++r) {
                int row = wr * 32 + mt * 16 + lg * 4 + r;
                int b = row * 256 + col * 2; b ^= ((row & 7) << 4);
                acc[mt][ntl][r] = bf2f(*reinterpret_cast<const ushortT*>(uBase + b));
            }
        }
#pragma unroll
    for (int ks = 0; ks < 4; ++ks) {
        int kk = ks * 32 + lg * 8;
        bf16x8 a0 = lds_a(aBase, 256, wr * 32 + l15,      kk * 2, 7);
        bf16x8 a1 = lds_a(aBase, 256, wr * 32 + 16 + l15, kk * 2, 7);
#pragma unroll
        for (int ntl = 0; ntl < 4; ++ntl) {
            int n = wc * 64 + ntl * 16 + l15;
            bf16x8 b = *reinterpret_cast<const bf16x8*>(wT + (size_t)n * 256 + kk);
            acc[0][ntl] = MFMA16(a0, b, acc[0][ntl]);
            acc[1][ntl] = MFMA16(a1, b, acc[1][ntl]);
        }
    }
}

__device__ inline void wfrag(char* base, int wr, int wc, int l15, int lg,
                             f32x4 acc[2][4], bool relu) {
#pragma unroll
    for (int mt = 0; mt < 2; ++mt)
#pragma unroll
        for (int ntl = 0; ntl < 4; ++ntl) {
            int col = wc * 64 + ntl * 16 + l15;
#pragma unroll
            for (int r = 0; r < 4; ++r) {
                int row = wr * 32 + mt * 16 + lg * 4 + r;
                int b = row * 256 + col * 2;
                b ^= ((row & 7) << 4);
                float v = acc[mt][ntl][r];
                if (relu) v = fmaxf(v, 0.f);
                *reinterpret_cast<ushortT*>(base + b) = f2bf(v);
            }
        }
}

// ---------------- A: edge kernel (r10 structure, 64-edge tile, 256 thr) -------
// LDS ~34 KB -> 4 blocks/CU (vs 2 at 128-tile): 4 independent barrier domains.
template<int EMBED, int LASTL>
__global__ __launch_bounds__(256) void edgeA_kernel(
        const ushortT* __restrict__ u, ushortT* __restrict__ e,
        const int* __restrict__ srcS, const int* __restrict__ dstS,
        const int* __restrict__ basep, const int* __restrict__ perm,
        const float* __restrict__ ea,
        const ushortT* __restrict__ eewT, const float* __restrict__ eeb,
        const ushortT* __restrict__ ew1t, const float* __restrict__ eb1,
        const ushortT* __restrict__ ew2t, const float* __restrict__ eb2,
        const ushortT* __restrict__ nw1bt,   // nw1t_l + 128 (KS=256)
        ushortT* __restrict__ partials) {
    __shared__ __align__(16) char eT[TE * 256];   // 16 KB
    __shared__ __align__(16) char uT[TE * 256];   // 16 KB
    __shared__ int dstx[TE], bstartL[TE], sidx[TE], pidx[TE];

    const int e0 = blockIdx.x * TE;
    int V = EE - e0; if (V > TE) V = TE;
    const int tid = threadIdx.x;
    const bf16x8 z8 = {0, 0, 0, 0, 0, 0, 0, 0};

    if (tid < TE) {
        int ii = e0 + tid;
        int d = (ii < EE) ? dstS[ii] : -1;
        dstx[tid] = d;
        bstartL[tid] = (d >= 0) ? basep[d] : 0;
        sidx[tid] = (ii < EE) ? srcS[ii] : 0;
        if (EMBED) pidx[tid] = (ii < EE) ? perm[ii] : 0;
    }
    __syncthreads();

    // stage u[src] -> uT (bf16 swz7): 64 rows x 16 chunks = 1024, 4 iters
#pragma unroll
    for (int s = 0; s < 4; ++s) {
        int idx = tid + s * 256;
        int row = idx >> 4, c8 = (idx & 15) * 8;
        bf16x8 v = *reinterpret_cast<const bf16x8*>(u + (size_t)sidx[row] * HH + c8);
        int b = row * 256 + c8 * 2; b ^= ((row & 7) << 4);
        *reinterpret_cast<bf16x8*>(uT + b) = v;
    }
    if (EMBED) {
        // stage ea[perm] -> eT as [64][32] bf16 swz3 (zero-padded K): 256 chunks
        {
            int row = tid >> 2, q4 = (tid & 3) * 4;
            float4 v = *reinterpret_cast<const float4*>(
                ea + (size_t)pidx[row] * EDIM + q4);
            unsigned long long pack =
                (unsigned long long)f2bf(v.x) |
                ((unsigned long long)f2bf(v.y) << 16) |
                ((unsigned long long)f2bf(v.z) << 32) |
                ((unsigned long long)f2bf(v.w) << 48);
            int b = row * 64 + q4 * 2; b ^= ((row & 3) << 4);
            *reinterpret_cast<unsigned long long*>(eT + b) = pack;
        }
        if (tid < 128) {
            int row = tid >> 1;
            int b = row * 64 + 32 + (tid & 1) * 16; b ^= ((row & 3) << 4);
            *reinterpret_cast<bf16x8*>(eT + b) = z8;
        }
    } else {
        // stage e -> eT (bf16 swz7)
#pragma unroll
        for (int s = 0; s < 4; ++s) {
            int idx = tid + s * 256;
            int row = idx >> 4, c8 = (idx & 15) * 8;
            bf16x8 v = *reinterpret_cast<const bf16x8*>(
                e + (size_t)(e0 + row) * HH + c8);
            int b = row * 256 + c8 * 2; b ^= ((row & 7) << 4);
            *reinterpret_cast<bf16x8*>(eT + b) = v;
        }
    }
    __syncthreads();

    const int wid = tid >> 6, lane = tid & 63;
    const int wr = wid >> 1, wc = wid & 1, l15 = lane & 15, lg = lane >> 4;
    f32x4 acc[2][4];

    if (EMBED) {
        gemm_b<32, 32, true>(eT, 64, 3, eewT, eeb, wr, wc, l15, lg, acc);
        __syncthreads();
        wfrag(eT, wr, wc, l15, lg, acc, false);
        __syncthreads();
    }
    // em1: hid = relu(e @ ew1 + eb1)
    gemm_b<HH, HH, true>(eT, 256, 7, ew1t, eb1, wr, wc, l15, lg, acc);
    __syncthreads();
    wfrag(eT, wr, wc, l15, lg, acc, true);
    __syncthreads();
    // em2: e' = hid @ ew2 + eb2
    gemm_b<HH, HH, true>(eT, 256, 7, ew2t, eb2, wr, wc, l15, lg, acc);
    __syncthreads();
    wfrag(eT, wr, wc, l15, lg, acc, false);
    __syncthreads();
    // e' copy-out (read-only on eT, store drain hides under G3 compute)
    if (!LASTL) {
#pragma unroll
        for (int s = 0; s < 4; ++s) {
            int idx = tid + s * 256;
            int row = idx >> 4, c8 = (idx & 15) * 8;
            if (row < V) {
                int b = row * 256 + c8 * 2; b ^= ((row & 7) << 4);
                *reinterpret_cast<bf16x8*>(e + (size_t)(e0 + row) * HH + c8) =
                    *reinterpret_cast<const bf16x8*>(eT + b);
            }
        }
    }
    // G3: hidden = relu(u + e' @ W1b)
    gemm_uinit3(eT, uT, nw1bt, wr, wc, l15, lg, acc);
    __syncthreads();
    wfrag(eT, wr, wc, l15, lg, acc, true);
    __syncthreads();

    // segmented sum of hidden by dst: 128 cols x 2 segs of 32 rows, plain stores
    {
        int col = tid & 127, seg = tid >> 7;
        int r = seg * 32, rend = r + 32;
        float sum = 0.f;
        int dprev = -1, runStart = r;
        for (; r < rend; ++r) {
            int d = dstx[r];
            if (d != dprev) {
                if (dprev >= 0) {
                    int slot = ((e0 + runStart) >> 5) - (bstartL[runStart] >> 5);
                    if (slot < 3)
                        partials[((size_t)slot * NN + dprev) * HH + col] = f2bf(sum);
                }
                sum = 0.f; dprev = d; runStart = r;
            }
            if (d >= 0) {
                int b = r * 256 + col * 2; b ^= ((r & 7) << 4);
                sum += bf2f(*reinterpret_cast<const ushortT*>(eT + b));
            }
        }
        if (dprev >= 0) {
            int slot = ((e0 + runStart) >> 5) - (bstartL[runStart] >> 5);
            if (slot < 3)
                partials[((size_t)slot * NN + dprev) * HH + col] = f2bf(sum);
        }
    }
}

// ---------------- B: node kernel (r10 verbatim) ----------------
template<int HASU>
__global__ __launch_bounds__(512) void nodeB_kernel(
        const ushortT* __restrict__ partials, const int* __restrict__ basep,
        const ushortT* __restrict__ w2g, const float* __restrict__ nb2g,
        float* __restrict__ h,
        const ushortT* __restrict__ w1tn, const float* __restrict__ b1n,
        ushortT* __restrict__ uOut) {
    __shared__ __align__(16) char sT[128 * 256];
    __shared__ int degx[128];
    __shared__ int basex[128];
    const int n0 = blockIdx.x * 128;
    int V = NN - n0; if (V > 128) V = 128;
    const int tid = threadIdx.x;

    if (tid < 128) {
        int bs = 0, de = 0;
        if (tid < V) {
            int n = n0 + tid;
            bs = basep[n];
            int be = (n + 1 < NN) ? basep[n + 1] : EE;
            de = be - bs;
        }
        basex[tid] = bs;
        degx[tid] = de;
    }
    __syncthreads();

#pragma unroll
    for (int g = 0; g < 4; ++g) {
        int node = g * 32 + (tid >> 4);
        int c8 = (tid & 15) * 8;
        float s[8] = {0.f, 0.f, 0.f, 0.f, 0.f, 0.f, 0.f, 0.f};
        if (node < V) {
            int bs = basex[node], de = degx[node];
            if (de > 0) {
                int ns = ((bs + de - 1) >> 5) - (bs >> 5) + 1;
                if (ns > 3) ns = 3;
                for (int sl = 0; sl < ns; ++sl) {
                    bf16x8 pv = *reinterpret_cast<const bf16x8*>(
                        partials + ((size_t)sl * NN + n0 + node) * HH + c8);
#pragma unroll
                    for (int j = 0; j < 8; ++j) s[j] += bf2f((ushortT)pv[j]);
                }
            }
        }
        bf16x8 o;
#pragma unroll
        for (int j = 0; j < 8; ++j) o[j] = f2bfs(s[j]);
        int b = node * 256 + c8 * 2; b ^= ((node & 7) << 4);
        *reinterpret_cast<bf16x8*>(sT + b) = o;
    }
    __syncthreads();

    const int wid = tid >> 6, lane = tid & 63;
    const int wr = wid >> 1, wc = wid & 1, l15 = lane & 15, lg = lane >> 4;
    f32x4 acc[2][4];

    gemm_b<HH, HH, false>(sT, 256, 7, w2g, nullptr, wr, wc, l15, lg, acc);
#pragma unroll
    for (int ntl = 0; ntl < 4; ++ntl) {
        int col = wc * 64 + ntl * 16 + l15;
        float bg = nb2g[col];
#pragma unroll
        for (int mt = 0; mt < 2; ++mt)
#pragma unroll
            for (int r = 0; r < 4; ++r) {
                int row = wr * 32 + mt * 16 + lg * 4 + r;
                if (row < V) {
                    size_t off = (size_t)(n0 + row) * HH + col;
                    float hn = h[off] + acc[mt][ntl][r] + (float)degx[row] * bg;
                    h[off] = hn;
                    acc[mt][ntl][r] = hn;
                } else {
                    acc[mt][ntl][r] = 0.f;
                }
            }
    }
    if (HASU) {
        __syncthreads();
        wfrag(sT, wr, wc, l15, lg, acc, false);
        __syncthreads();
        gemm_b<HH, 2 * HH, true>(sT, 256, 7, w1tn, b1n, wr, wc, l15, lg, acc);
        __syncthreads();
        wfrag(sT, wr, wc, l15, lg, acc, false);
        __syncthreads();
#pragma unroll
        for (int s = 0; s < 4; ++s) {
            int idx = tid + s * 512;
            int row = idx >> 4, c8 = (idx & 15) * 8;
            if (row < V) {
                int b = row * 256 + c8 * 2; b ^= ((row & 7) << 4);
                *reinterpret_cast<bf16x8*>(uOut + (size_t)(n0 + row) * HH + c8) =
                    *reinterpret_cast<const bf16x8*>(sT + b);
            }
        }
    }
}

// ---------------- node_pre2 (r10 verbatim, wave grid 4x2 over 128 rows) -------
__global__ __launch_bounds__(512) void node_pre2_kernel(
        const float* __restrict__ x, const ushortT* __restrict__ newT,
        const float* __restrict__ neb,
        const ushortT* __restrict__ w1t, const float* __restrict__ b1,
        float* __restrict__ h, ushortT* __restrict__ uo) {
    __shared__ __align__(16) char sT[128 * 256];   // 32 KB
    __shared__ __align__(16) char xT[128 * 64];    // 8 KB, [128][32] bf16 swz3
    const int n0 = blockIdx.x * 128;
    int V = NN - n0; if (V > 128) V = 128;
    const int tid = threadIdx.x;

    // stage x -> xT : 1024 float4 chunks, 2 per thread
#pragma unroll
    for (int s = 0; s < 2; ++s) {
        int idx = tid + s * 512;
        int row = idx >> 3;
        int q4 = (idx & 7) * 4;
        unsigned long long pack = 0ull;
        if (row < V) {
            float4 v = *reinterpret_cast<const float4*>(
                x + (size_t)(n0 + row) * NDIM + q4);
            pack = (unsigned long long)f2bf(v.x) |
                   ((unsigned long long)f2bf(v.y) << 16) |
                   ((unsigned long long)f2bf(v.z) << 32) |
                   ((unsigned long long)f2bf(v.w) << 48);
        }
        int b = row * 64 + q4 * 2; b ^= ((row & 3) << 4);
        *reinterpret_cast<unsigned long long*>(xT + b) = pack;
    }
    __syncthreads();

    const int wid = tid >> 6, lane = tid & 63;
    // 128 rows: use wr in [0,4) x wc in [0,2)
    const int wr = wid >> 1, wc = wid & 1, l15 = lane & 15, lg = lane >> 4;
    f32x4 acc[2][4];
    // two row-halves per wave pair: reuse gemm with wr in 0..3 => rows wr*32
    gemm_b<32, 32, true>(xT, 64, 3, newT, neb, (wid >> 1), wc, l15, lg, acc);
#pragma unroll
    for (int mt = 0; mt < 2; ++mt)
#pragma unroll
        for (int ntl = 0; ntl < 4; ++ntl) {
            int col = wc * 64 + ntl * 16 + l15;
#pragma unroll
            for (int r = 0; r < 4; ++r) {
                int row = (wid >> 1) * 32 + mt * 16 + lg * 4 + r;
                if (row < V) h[(size_t)(n0 + row) * HH + col] = acc[mt][ntl][r];
            }
        }
    wfrag(sT, wr, wc, l15, lg, acc, false);
    __syncthreads();
    gemm_b<HH, 2 * HH, true>(sT, 256, 7, w1t, b1, wr, wc, l15, lg, acc);
    __syncthreads();
    wfrag(sT, wr, wc, l15, lg, acc, false);
    __syncthreads();
#pragma unroll
    for (int s = 0; s < 4; ++s) {
        int idx = tid + s * 512;
        int row = idx >> 4, c8 = (idx & 15) * 8;
        if (row < V) {
            int b = row * 256 + c8 * 2; b ^= ((row & 7) << 4);
            *reinterpret_cast<bf16x8*>(uo + (size_t)(n0 + row) * HH + c8) =
                *reinterpret_cast<const bf16x8*>(sT + b);
        }
    }
}

// ---------------- pool (group-sorted, atomic-free) + readout ----------------
__global__ __launch_bounds__(256) void pool2_kernel(
        const float* __restrict__ h, const int* __restrict__ gperm,
        const int* __restrict__ gbase, const int* __restrict__ gcounts,
        float* __restrict__ pooled) {
    int w = threadIdx.x >> 6, lane = threadIdx.x & 63;
    int g = blockIdx.x * 4 + w;
    int bs = gbase[g], cnt = gcounts[g];
    int c = lane * 2;
    float ax = 0.f, ay = 0.f;
    for (int j = 0; j < cnt; ++j) {
        int n = gperm[bs + j];
        float2 v = *reinterpret_cast<const float2*>(h + (size_t)n * HH + c);
        ax += v.x; ay += v.y;
    }
    float2 o = {ax, ay};
    *reinterpret_cast<float2*>(pooled + (size_t)g * HH + c) = o;
}

__global__ __launch_bounds__(128) void readout_kernel(
        const float* __restrict__ pooled,
        const float* __restrict__ w1, const float* __restrict__ b1,
        const float* __restrict__ w2, const float* __restrict__ b2,
        float* __restrict__ out) {
    __shared__ float row[HH];
    __shared__ float red[HH];
    int g = blockIdx.x, j = threadIdx.x;
    row[j] = pooled[(size_t)g * HH + j];
    __syncthreads();
    float acc = b1[j];
    for (int k = 0; k < HH; ++k) acc += row[k] * w1[k * HH + j];
    red[j] = fmaxf(acc, 0.f) * w2[j];
    __syncthreads();
    for (int s = 64; s > 0; s >>= 1) {
        if (j < s) red[j] += red[j + s];
        __syncthreads();
    }
    if (j == 0) out[g] = red[0] + b2[0];
}

extern "C" void kernel_launch(void* const* d_in, const int* in_sizes, int n_in,
                              void* d_out, int out_size, void* d_ws, size_t ws_size,
                              hipStream_t stream) {
    const float* x     = (const float*)d_in[0];
    const int*   ei    = (const int*)d_in[1];
    const float* ea    = (const float*)d_in[2];
    const int*   batch = (const int*)d_in[3];
    const float* ne_w  = (const float*)d_in[4];
    const float* ne_b  = (const float*)d_in[5];
    const float* ee_w  = (const float*)d_in[6];
    const float* ee_b  = (const float*)d_in[7];
    const float* nm_w1 = (const float*)d_in[8];
    const float* nm_b1 = (const float*)d_in[9];
    const float* nm_w2 = (const float*)d_in[10];
    const float* nm_b2 = (const float*)d_in[11];
    const float* bn_g  = (const float*)d_in[12];
    const float* bn_b  = (const float*)d_in[13];
    const float* em_w1 = (const float*)d_in[14];
    const float* em_b1 = (const float*)d_in[15];
    const float* em_w2 = (const float*)d_in[16];
    const float* em_b2 = (const float*)d_in[17];
    const float* ro_w1 = (const float*)d_in[18];
    const float* ro_b1 = (const float*)d_in[19];
    const float* ro_w2 = (const float*)d_in[20];
    const float* ro_b2 = (const float*)d_in[21];

    const int* srcp = ei;
    const int* dstp = ei + EE;

    // workspace carve (16B aligned) — total ~214 MB
    char* p = (char*)d_ws;
    float* h = (float*)p;            p += (size_t)NN * HH * 4;
    float* pooled = (float*)p;       p += (size_t)GG * HH * 4;
    ushortT* ebuf = (ushortT*)p;     p += (size_t)EE * HH * 2;
    ushortT* ubuf = (ushortT*)p;     p += (size_t)NN * HH * 2;
    ushortT* partials = (ushortT*)p; p += (size_t)3 * NN * HH * 2;
    ushortT* ew1t = (ushortT*)p;     p += (size_t)LL * HH * HH * 2;
    ushortT* ew2t = (ushortT*)p;     p += (size_t)LL * HH * HH * 2;
    ushortT* nw1t = (ushortT*)p;     p += (size_t)LL * 2 * HH * HH * 2;
    ushortT* w2g  = (ushortT*)p;     p += (size_t)LL * HH * HH * 2;
    float* nb2g   = (float*)p;       p += (size_t)LL * HH * 4;
    ushortT* eewT = (ushortT*)p;     p += (size_t)HH * 32 * 2;
    ushortT* newT = (ushortT*)p;     p += (size_t)HH * 32 * 2;
    int* perm   = (int*)p;           p += (size_t)EE * 4;
    int* srcS   = (int*)p;           p += (size_t)EE * 4;
    int* dstS   = (int*)p;           p += (size_t)EE * 4;
    int* counts = (int*)p;           p += (size_t)NN * 4;
    int* basep  = (int*)p;           p += (size_t)NN * 4;
    int* cnt    = (int*)p;           p += (size_t)NN * 4;
    int* bsum   = (int*)p;           p += (size_t)SCAN_NB * 4;
    int* bbase  = (int*)p;           p += (size_t)SCAN_NB * 4;
    int* gperm  = (int*)p;           p += (size_t)NN * 4;
    int* gcounts= (int*)p;           p += (size_t)GG * 4;
    int* gbase  = (int*)p;           p += (size_t)GG * 4;
    int* gcnt   = (int*)p;           p += (size_t)GG * 4;

    // ---- sort edges by dst ----
    hipMemsetAsync(counts, 0, (size_t)NN * 4, stream);
    hipMemsetAsync(cnt, 0, (size_t)NN * 4, stream);
    hipMemsetAsync(gcounts, 0, (size_t)GG * 4, stream);
    hipMemsetAsync(gcnt, 0, (size_t)GG * 4, stream);
    hist_kernel<<<(EE + 255) / 256, 256, 0, stream>>>(dstp, counts);
    scan_part1<<<SCAN_NB, 256, 0, stream>>>(counts, bsum);
    scan_part2<<<1, 256, 0, stream>>>(bsum, bbase);
    scan_part3<<<SCAN_NB, 256, 0, stream>>>(counts, bbase, basep);
    build_perm_kernel<<<(EE + 255) / 256, 256, 0, stream>>>(
        srcp, dstp, basep, cnt, perm, srcS, dstS);

    // ---- sort nodes by batch group (for atomic-free pooling) ----
    ghist_kernel<<<(NN + 255) / 256, 256, 0, stream>>>(batch, gcounts);
    gscan_kernel<<<1, 1024, 0, stream>>>(gcounts, gbase);
    gbuild_kernel<<<(NN + 255) / 256, 256, 0, stream>>>(batch, gbase, gcnt, gperm);

    // ---- weight prep ----
    const float inv_std = 1.0f / sqrtf(1.0f + 1e-5f);
    transpose_kernel<<<(LL * HH * HH + 255) / 256, 256, 0, stream>>>(em_w1, ew1t, HH, HH);
    transpose_kernel<<<(LL * HH * HH + 255) / 256, 256, 0, stream>>>(em_w2, ew2t, HH, HH);
    transpose_kernel<<<(LL * 2 * HH * HH + 255) / 256, 256, 0, stream>>>(nm_w1, nw1t, 2 * HH, HH);
    bnfold_kernel<<<(LL * HH * HH + 255) / 256, 256, 0, stream>>>(
        nm_w2, nm_b2, bn_g, bn_b, w2g, nb2g, inv_std);
    transpose_pad32_kernel<<<(HH * 32 + 255) / 256, 256, 0, stream>>>(ee_w, eewT, EDIM);
    transpose_pad32_kernel<<<(HH * 32 + 255) / 256, 256, 0, stream>>>(ne_w, newT, NDIM);

    // ---- node embed + u0 (fused) ----
    node_pre2_kernel<<<NB2, 512, 0, stream>>>(x, newT, ne_b, nw1t, nm_b1, h, ubuf);

    // ---- layers ----
    for (int l = 0; l < LL; ++l) {
        const ushortT* nw1bt = nw1t + (size_t)l * 2 * HH * HH + 128;
        if (l == 0) {
            edgeA_kernel<1, 0><<<NTE, 256, 0, stream>>>(
                ubuf, ebuf, srcS, dstS, basep, perm, ea, eewT, ee_b,
                ew1t + (size_t)l * HH * HH, em_b1 + l * HH,
                ew2t + (size_t)l * HH * HH, em_b2 + l * HH,
                nw1bt, partials);
        } else if (l < LL - 1) {
            edgeA_kernel<0, 0><<<NTE, 256, 0, stream>>>(
                ubuf, ebuf, srcS, dstS, basep, perm, ea, eewT, ee_b,
                ew1t + (size_t)l * HH * HH, em_b1 + l * HH,
                ew2t + (size_t)l * HH * HH, em_b2 + l * HH,
                nw1bt, partials);
        } else {
            edgeA_kernel<0, 1><<<NTE, 256, 0, stream>>>(
                ubuf, ebuf, srcS, dstS, basep, perm, ea, eewT, ee_b,
                ew1t + (size_t)l * HH * HH, em_b1 + l * HH,
                ew2t + (size_t)l * HH * HH, em_b2 + l * HH,
                nw1bt, partials);
        }
        if (l < LL - 1) {
            nodeB_kernel<1><<<NB2, 512, 0, stream>>>(
                partials, basep, w2g + (size_t)l * HH * HH, nb2g + l * HH, h,
                nw1t + (size_t)(l + 1) * 2 * HH * HH, nm_b1 + (l + 1) * HH, ubuf);
        } else {
            nodeB_kernel<0><<<NB2, 512, 0, stream>>>(
                partials, basep, w2g + (size_t)l * HH * HH, nb2g + l * HH, h,
                nw1t, nm_b1, ubuf);
        }
    }

    // ---- pool + readout ----
    pool2_kernel<<<GG / 4, 256, 0, stream>>>(h, gperm, gbase, gcounts, pooled);
    readout_kernel<<<GG, 128, 0, stream>>>(pooled, ro_w1, ro_b1, ro_w2, ro_b2,
                                           (float*)d_out);
}